// Round 3
// baseline (528.759 us; speedup 1.0000x reference)
//
#include <hip/hip_runtime.h>

// out[b, j1*64 + j2] = x[b,0,j1] * x[b,1,j2]
// row of x = 128 floats (a[0..63] = x[b,0,:], c[0..63] = x[b,1,:])
// output row = 4096 floats = 1024 float4.

typedef float f32x4 __attribute__((ext_vector_type(4)));

__global__ __launch_bounds__(256) void anfis_rule_strength_kernel(
    const float* __restrict__ x, float* __restrict__ out, int batch)
{
    __shared__ float s_a[64];
    __shared__ float s_c[64];

    const int b = blockIdx.x;
    if (b >= batch) return;
    const int t = threadIdx.x;

    // Stage the 128-float input row into LDS (coalesced load).
    if (t < 128) {
        const float v = x[(size_t)b * 128 + t];
        if (t < 64) s_a[t] = v;
        else        s_c[t - 64] = v;
    }
    __syncthreads();

    // Each thread's fixed c-fragment: 4 consecutive c values (ds_read_b128,
    // 16 distinct addresses x 4-lane broadcast -> conflict-free).
    const f32x4 c4 = *reinterpret_cast<const f32x4*>(&s_c[(t & 15) * 4]);

    f32x4* o = reinterpret_cast<f32x4*>(out) + (size_t)b * 1024 + t;

    #pragma unroll
    for (int s = 0; s < 4; ++s) {
        // float4 index within row = s*256 + t  (lane-consecutive per store)
        const float a = s_a[(s * 256 + t) >> 4];
        f32x4 r;
        r.x = a * c4.x;
        r.y = a * c4.y;
        r.z = a * c4.z;
        r.w = a * c4.w;
        // Write-once streaming output: don't pollute L2/LLC.
        __builtin_nontemporal_store(r, o + s * 256);
    }
}

extern "C" void kernel_launch(void* const* d_in, const int* in_sizes, int n_in,
                              void* d_out, int out_size, void* d_ws, size_t ws_size,
                              hipStream_t stream)
{
    const float* x = (const float*)d_in[0];
    float* out = (float*)d_out;
    const int batch = in_sizes[0] / 128;   // x is [B, 2, 64] floats
    anfis_rule_strength_kernel<<<batch, 256, 0, stream>>>(x, out, batch);
}